// Round 2
// baseline (211.235 us; speedup 1.0000x reference)
//
#include <hip/hip_runtime.h>

#define N_SEL 8192
#define SUB_SZ 32
#define N_SUB 256
#define N_GRAPH 64
#define N_FULL 12288
#define E_RAW 262144
#define N_PERS 4
#define D 128
#define EPSILON 0.1f
#define LAMB1 0.5f

// Custom zero-fill: grid-stride float4 stores at the write roofline.
__global__ __launch_bounds__(256) void zero_kernel(float4* __restrict__ out, int n4)
{
    int idx    = blockIdx.x * 256 + threadIdx.x;
    int stride = gridDim.x * 256;
    const float4 z = make_float4(0.f, 0.f, 0.f, 0.f);
    for (int i = idx; i < n4; i += stride)
        out[i] = z;
}

// One block (256 threads) per subgraph: compute the 32x32 weighted-cosine
// block, threshold, row-scale, and scatter nonzeros into the dense output.
__global__ __launch_bounds__(256) void subgraph_kernel(
        const float* __restrict__ x,          // [N_SEL, D]
        const float* __restrict__ Wc,         // [N_PERS, D]
        const float* __restrict__ sscore,     // [N_SUB]
        const int*   __restrict__ smap,       // [N_SEL]
        float* __restrict__ out)              // [N_FULL, N_FULL], pre-zeroed
{
    const int s    = blockIdx.x;      // subgraph id
    const int base = s * SUB_SZ;
    const int tid  = threadIdx.x;

    __shared__ float xs[SUB_SZ][D + 1];        // +1 pad: conflict-free column reads
    __shared__ float w2[N_PERS][D];            // Wc^2
    __shared__ float rnorm[N_PERS][SUB_SZ];    // 1/norm per (perspective, node)
    __shared__ int   map_s[SUB_SZ];
    __shared__ float rowscore;

    // stage x tile (32x128 floats), coalesced global reads
    for (int k = tid; k < SUB_SZ * D; k += 256) {
        int i = k >> 7;        // k / 128
        int d = k & (D - 1);   // k % 128
        xs[i][d] = x[(base + i) * D + d];
    }
    // Wc^2
    for (int k = tid; k < N_PERS * D; k += 256) {
        float w = Wc[k];
        ((float*)w2)[k] = w * w;
    }
    if (tid < SUB_SZ) map_s[tid] = smap[base + tid];
    if (tid == 0) {
        int g4 = (s >> 2) << 2;   // first subgraph of this graph
        float sum = sscore[g4] + sscore[g4 + 1] + sscore[g4 + 2] + sscore[g4 + 3];
        rowscore = (sscore[s] / sum) * LAMB1;
    }
    __syncthreads();

    // per-(perspective, node) inverse norms: 128 tasks
    if (tid < N_PERS * SUB_SZ) {
        int p = tid >> 5;
        int i = tid & 31;
        float acc = 0.f;
        #pragma unroll 8
        for (int d = 0; d < D; ++d) {
            float v = xs[i][d];
            acc = fmaf(v * v, w2[p][d], acc);
        }
        float n = fmaxf(sqrtf(acc), 1e-12f);
        rnorm[p][i] = 1.0f / n;
    }
    __syncthreads();

    // 1024 (i,j) entries, 4 per thread
    for (int e = tid; e < SUB_SZ * SUB_SZ; e += 256) {
        int i = e >> 5;
        int j = e & 31;
        if (i == j) continue;                  // RemoveSelfLoop
        float a0 = 0.f, a1 = 0.f, a2 = 0.f, a3 = 0.f;
        #pragma unroll 8
        for (int d = 0; d < D; ++d) {
            float prod = xs[i][d] * xs[j][d];
            a0 = fmaf(prod, w2[0][d], a0);
            a1 = fmaf(prod, w2[1][d], a1);
            a2 = fmaf(prod, w2[2][d], a2);
            a3 = fmaf(prod, w2[3][d], a3);
        }
        float adj = 0.25f * (a0 * rnorm[0][i] * rnorm[0][j] +
                             a1 * rnorm[1][i] * rnorm[1][j] +
                             a2 * rnorm[2][i] * rnorm[2][j] +
                             a3 * rnorm[3][i] * rnorm[3][j]);
        if (adj > EPSILON) {                   // EpsilonNN (zeros skipped: out pre-zeroed)
            long long row = map_s[i];
            long long col = map_s[j];
            out[row * (long long)N_FULL + col] = adj * rowscore;  // unique targets
        }
    }
}

__global__ __launch_bounds__(256) void raw_edge_kernel(
        const int* __restrict__ ei, float* __restrict__ out)
{
    int e = blockIdx.x * blockDim.x + threadIdx.x;
    if (e < E_RAW) {
        long long r = ei[e];
        long long c = ei[E_RAW + e];
        atomicAdd(&out[r * (long long)N_FULL + c], 1.0f - LAMB1);
    }
}

extern "C" void kernel_launch(void* const* d_in, const int* in_sizes, int n_in,
                              void* d_out, int out_size, void* d_ws, size_t ws_size,
                              hipStream_t stream) {
    const float* x      = (const float*)d_in[0];   // [8192,128]
    const float* Wc     = (const float*)d_in[1];   // [4,128]
    const float* sscore = (const float*)d_in[2];   // [256]
    const int* smap = (const int*)d_in[4];         // [8192]
    const int* rei  = (const int*)d_in[7];         // [2, 262144]
    float* out = (float*)d_out;

    // 1) zero the dense 12288^2 output (the HBM-write floor) — custom fill,
    //    rocclr's fillBufferAligned only hit ~1.6 TB/s at this size.
    int n4 = out_size / 4;                         // 37,748,736 float4s
    zero_kernel<<<2048, 256, 0, stream>>>((float4*)out, n4);

    // 2) intra-subgraph weighted-cosine blocks -> unique plain stores
    subgraph_kernel<<<N_SUB, 256, 0, stream>>>(x, Wc, sscore, smap, out);

    // 3) raw-edge coalesce: atomic +0.5 (handles duplicates + overlaps)
    raw_edge_kernel<<<E_RAW / 256, 256, 0, stream>>>(rei, out);
}

// Round 3
// 160.253 us; speedup vs baseline: 1.3181x; 1.3181x over previous
//
#include <hip/hip_runtime.h>

#define N_SEL 8192
#define SUB_SZ 32
#define N_SUB 256
#define N_GRAPH 64
#define N_FULL 12288
#define E_RAW 262144
#define N_PERS 4
#define D 128
#define EPSILON 0.1f
#define LAMB1 0.5f

// 12288*12288 floats = 37,748,736 float4s
#define N4_TOTAL 37748736
#define FILL_BLOCKS 4096
#define PER_BLOCK (N4_TOTAL / FILL_BLOCKS)   // 9216 float4s per block (144 KB)
#define FILL_ITERS (PER_BLOCK / 256)         // 36

typedef float f4_t __attribute__((ext_vector_type(4)));

// Contiguous-chunk zero fill with nontemporal (streaming) 16B stores.
// Each block walks its own 144 KB span sequentially -> DRAM-friendly streams.
__global__ __launch_bounds__(256) void zero_kernel(f4_t* __restrict__ out)
{
    size_t base = (size_t)blockIdx.x * PER_BLOCK + threadIdx.x;
    const f4_t z = (f4_t){0.f, 0.f, 0.f, 0.f};
    #pragma unroll
    for (int k = 0; k < FILL_ITERS; ++k)
        __builtin_nontemporal_store(z, &out[base + (size_t)k * 256]);
}

// Merged scatter: blocks [0,256) do the subgraph cosine blocks (atomicAdd so
// they commute with raw edges); blocks [256,1280) do raw-edge +0.5 adds.
__global__ __launch_bounds__(256) void scatter_kernel(
        const float* __restrict__ x,          // [N_SEL, D]
        const float* __restrict__ Wc,         // [N_PERS, D]
        const float* __restrict__ sscore,     // [N_SUB]
        const int*   __restrict__ smap,       // [N_SEL]
        const int*   __restrict__ rei,        // [2, E_RAW]
        float* __restrict__ out)              // [N_FULL, N_FULL], pre-zeroed
{
    const int tid = threadIdx.x;

    if (blockIdx.x >= N_SUB) {
        // ---- raw-edge half: one atomic per thread ----
        int e = (blockIdx.x - N_SUB) * 256 + tid;
        long long r = rei[e];
        long long c = rei[E_RAW + e];
        atomicAdd(&out[r * (long long)N_FULL + c], 1.0f - LAMB1);
        return;
    }

    // ---- subgraph half ----
    const int s    = blockIdx.x;
    const int base = s * SUB_SZ;

    __shared__ float xs[SUB_SZ][D + 1];
    __shared__ float w2[N_PERS][D];
    __shared__ float rnorm[N_PERS][SUB_SZ];
    __shared__ int   map_s[SUB_SZ];
    __shared__ float rowscore;

    for (int k = tid; k < SUB_SZ * D; k += 256) {
        int i = k >> 7;
        int d = k & (D - 1);
        xs[i][d] = x[(base + i) * D + d];
    }
    for (int k = tid; k < N_PERS * D; k += 256) {
        float w = Wc[k];
        ((float*)w2)[k] = w * w;
    }
    if (tid < SUB_SZ) map_s[tid] = smap[base + tid];
    if (tid == 0) {
        int g4 = (s >> 2) << 2;
        float sum = sscore[g4] + sscore[g4 + 1] + sscore[g4 + 2] + sscore[g4 + 3];
        rowscore = (sscore[s] / sum) * LAMB1;
    }
    __syncthreads();

    if (tid < N_PERS * SUB_SZ) {
        int p = tid >> 5;
        int i = tid & 31;
        float acc = 0.f;
        #pragma unroll 8
        for (int d = 0; d < D; ++d) {
            float v = xs[i][d];
            acc = fmaf(v * v, w2[p][d], acc);
        }
        rnorm[p][i] = 1.0f / fmaxf(sqrtf(acc), 1e-12f);
    }
    __syncthreads();

    for (int e = tid; e < SUB_SZ * SUB_SZ; e += 256) {
        int i = e >> 5;
        int j = e & 31;
        if (i == j) continue;
        float a0 = 0.f, a1 = 0.f, a2 = 0.f, a3 = 0.f;
        #pragma unroll 8
        for (int d = 0; d < D; ++d) {
            float prod = xs[i][d] * xs[j][d];
            a0 = fmaf(prod, w2[0][d], a0);
            a1 = fmaf(prod, w2[1][d], a1);
            a2 = fmaf(prod, w2[2][d], a2);
            a3 = fmaf(prod, w2[3][d], a3);
        }
        float adj = 0.25f * (a0 * rnorm[0][i] * rnorm[0][j] +
                             a1 * rnorm[1][i] * rnorm[1][j] +
                             a2 * rnorm[2][i] * rnorm[2][j] +
                             a3 * rnorm[3][i] * rnorm[3][j]);
        if (adj > EPSILON) {
            long long row = map_s[i];
            long long col = map_s[j];
            atomicAdd(&out[row * (long long)N_FULL + col], adj * rowscore);
        }
    }
}

extern "C" void kernel_launch(void* const* d_in, const int* in_sizes, int n_in,
                              void* d_out, int out_size, void* d_ws, size_t ws_size,
                              hipStream_t stream) {
    const float* x      = (const float*)d_in[0];
    const float* Wc     = (const float*)d_in[1];
    const float* sscore = (const float*)d_in[2];
    const int* smap = (const int*)d_in[4];
    const int* rei  = (const int*)d_in[7];
    float* out = (float*)d_out;

    // 1) zero the dense 12288^2 output: contiguous chunks + nontemporal stores
    zero_kernel<<<FILL_BLOCKS, 256, 0, stream>>>((f4_t*)out);

    // 2) one merged scatter launch: subgraph cosine blocks + raw edges (atomic)
    scatter_kernel<<<N_SUB + E_RAW / 256, 256, 0, stream>>>(x, Wc, sscore, smap, rei, out);
}